// Round 3
// baseline (114.821 us; speedup 1.0000x reference)
//
#include <hip/hip_runtime.h>
#include <hip/hip_bf16.h>

// B=4, L=128, C=1024, D=512, fp32.
// out[b,l,c] = softmax_c( sum_d V[d]*tanh(wq[b,l,d] + uc[b,c,d]) )
// tanh(x) = 1 - 2/(e^{2x}+1);  e^{2(wq+uc)} = e^{2wq} * e^{2uc};
// softmax shift-invariance drops the constant sum(V):
//   align'[b,l,c] = sum_d (-2 V_d) * rcp(ewq[b,d,l]*euc[b,d,c] + 1)
//
// R3: LDS-free GEMM. Transposed form C[d][n] = sum_k W_t[k][d] * X[n][k]:
//  - weights are wave-uniform -> SGPR s_load operand (free pipe)
//  - X rows stream from global per-lane (L1 line reuse across k)
//  - 16 accs/lane, 64 n-cols/wave, no LDS, no barriers -> VALU-bound.
// fused_align3 also LDS-free: euc coalesced global, wq/V via s_load.

#define SCALE2 2.8853900817779268f  // 2*log2(e)

// ---------------------------------------------------------------------------
// 64x64 transpose of the two 512x512 weight matrices. blockIdx.z: 0=W, 1=U.
// ---------------------------------------------------------------------------
__global__ __launch_bounds__(256) void transpose512(
    const float* __restrict__ W, const float* __restrict__ U,
    float* __restrict__ Wt, float* __restrict__ Ut)
{
    __shared__ float t[64][65];
    const float* src = blockIdx.z ? U : W;
    float* dst = blockIdx.z ? Ut : Wt;
    const int bx = blockIdx.x * 64;   // src col block
    const int by = blockIdx.y * 64;   // src row block
    const int r  = threadIdx.x >> 2;         // 0..63
    const int c4 = (threadIdx.x & 3) * 16;   // 0,16,32,48
#pragma unroll
    for (int p = 0; p < 4; ++p) {
        float4 v = *(const float4*)(src + (size_t)(by + r) * 512 + bx + c4 + p * 4);
        t[r][c4 + p * 4 + 0] = v.x;
        t[r][c4 + p * 4 + 1] = v.y;
        t[r][c4 + p * 4 + 2] = v.z;
        t[r][c4 + p * 4 + 3] = v.w;
    }
    __syncthreads();
#pragma unroll
    for (int p = 0; p < 4; ++p) {
        float4 o;
        o.x = t[c4 + p * 4 + 0][r];
        o.y = t[c4 + p * 4 + 1][r];
        o.z = t[c4 + p * 4 + 2][r];
        o.w = t[c4 + p * 4 + 3][r];
        *(float4*)(dst + (size_t)(bx + r) * 512 + by + c4 + p * 4) = o;
    }
}

// ---------------------------------------------------------------------------
// LDS-free GEMM + exp2. One wave = 16 d-rows x 64 n-cols, K=512.
// waves 0..255: wq (X=hidden, N=512); waves 256..2303: uc (X=ctx, N=4096).
// mt is the fast grid dim so waves sharing an X-chunk are co-resident (L2).
// ---------------------------------------------------------------------------
__global__ __launch_bounds__(256) void gemm_sgpr_kernel(
    const float* __restrict__ hidden, const float* __restrict__ ctx,
    const float* __restrict__ Wt, const float* __restrict__ Ut,
    const float* __restrict__ U_b,
    float* __restrict__ ewq_t, float* __restrict__ euc_t)
{
    const int w    = __builtin_amdgcn_readfirstlane(threadIdx.x >> 6);
    const int lane = threadIdx.x & 63;
    const int g    = blockIdx.x * 4 + w;

    const float* At;     // [k][m] k-major transposed weights
    const float* X;      // row-major [n][512]
    const float* bias;   // per-m bias or null
    float* Cb;           // output base for (m0, col0)
    int m0;
    size_t ostride;

    if (g < 256) {
        const int mt = g & 31, nt = g >> 5;
        m0 = mt * 16;
        const int ncol0 = nt * 64;               // in [0,512)
        const int b = ncol0 >> 7, l0 = ncol0 & 127;
        At = Wt; bias = nullptr;
        X  = hidden + (size_t)ncol0 * 512;
        Cb = ewq_t + ((size_t)b * 512 + m0) * 128 + l0;
        ostride = 128;
    } else {
        const int gg = g - 256;
        const int mt = gg & 31, nt = gg >> 5;
        m0 = mt * 16;
        const int ncol0 = nt * 64;               // in [0,4096)
        const int b = ncol0 >> 10, c0 = ncol0 & 1023;
        At = Ut; bias = U_b;
        X  = ctx + (size_t)ncol0 * 512;
        Cb = euc_t + ((size_t)b * 512 + m0) * 1024 + c0;
        ostride = 1024;
    }

    float acc[16];
#pragma unroll
    for (int j = 0; j < 16; ++j) acc[j] = 0.0f;

    const float* xp = X + (size_t)lane * 512;

#pragma unroll 2
    for (int kb = 0; kb < 128; ++kb) {
        const float4 xv = *(const float4*)(xp + kb * 4);
        const float* wr = At + (size_t)kb * 2048 + m0;   // At[4k..][m0..]
#pragma unroll
        for (int j = 0; j < 16; ++j) acc[j] = fmaf(wr[j], xv.x, acc[j]);
#pragma unroll
        for (int j = 0; j < 16; ++j) acc[j] = fmaf(wr[512 + j], xv.y, acc[j]);
#pragma unroll
        for (int j = 0; j < 16; ++j) acc[j] = fmaf(wr[1024 + j], xv.z, acc[j]);
#pragma unroll
        for (int j = 0; j < 16; ++j) acc[j] = fmaf(wr[1536 + j], xv.w, acc[j]);
    }

#pragma unroll
    for (int j = 0; j < 16; ++j) {
        const float bl = bias ? bias[m0 + j] : 0.0f;
        Cb[(size_t)j * ostride + lane] =
            __builtin_amdgcn_exp2f(SCALE2 * (acc[j] + bl));
    }
}

// ---------------------------------------------------------------------------
// Fused align, LDS-free. Block = (64 c's, 16 l's, b); wave w owns 4 l's.
// Lane owns c = c0+lane; d-loop is lane-local; wq/V are wave-uniform s_loads.
// ---------------------------------------------------------------------------
__global__ __launch_bounds__(256) void fused_align3(
    const float* __restrict__ ewq_t,  // [4][512][128]
    const float* __restrict__ euc_t,  // [4][512][1024]
    const float* __restrict__ Vv,     // [512]
    float* __restrict__ out)          // [4][128][1024]
{
    const int w    = __builtin_amdgcn_readfirstlane(threadIdx.x >> 6);
    const int lane = threadIdx.x & 63;
    const int c0   = blockIdx.x * 64;
    const int l0   = blockIdx.y * 16 + w * 4;
    const int b    = blockIdx.z;

    const float* wqp = ewq_t + (size_t)b * 512 * 128 + l0;    // + d*128
    const float* ucp = euc_t + (size_t)b * 512 * 1024 + c0 + lane; // + d*1024

    float a0 = 0.f, a1 = 0.f, a2 = 0.f, a3 = 0.f;

#pragma unroll 8
    for (int d = 0; d < 512; ++d) {
        const float  e   = ucp[(size_t)d * 1024];
        const float4 q   = *(const float4*)(wqp + (size_t)d * 128);
        const float  vm2 = -2.0f * Vv[d];
        a0 = fmaf(vm2, __builtin_amdgcn_rcpf(fmaf(q.x, e, 1.0f)), a0);
        a1 = fmaf(vm2, __builtin_amdgcn_rcpf(fmaf(q.y, e, 1.0f)), a1);
        a2 = fmaf(vm2, __builtin_amdgcn_rcpf(fmaf(q.z, e, 1.0f)), a2);
        a3 = fmaf(vm2, __builtin_amdgcn_rcpf(fmaf(q.w, e, 1.0f)), a3);
    }

    float* op = out + ((size_t)b * 128 + l0) * 1024 + c0 + lane;
    op[0]    = a0;
    op[1024] = a1;
    op[2048] = a2;
    op[3072] = a3;
}

// in-place softmax over rows of 1024; one wave per row
__global__ __launch_bounds__(256) void softmax_kernel(float* __restrict__ data)
{
    const int row  = blockIdx.x * 4 + (threadIdx.x >> 6);
    const int lane = threadIdx.x & 63;
    float* p = data + (size_t)row * 1024;

    float4 x[4];
#pragma unroll
    for (int j = 0; j < 4; ++j) x[j] = *(const float4*)(p + j * 256 + lane * 4);

    float m = x[0].x;
#pragma unroll
    for (int j = 0; j < 4; ++j) {
        m = fmaxf(m, x[j].x); m = fmaxf(m, x[j].y);
        m = fmaxf(m, x[j].z); m = fmaxf(m, x[j].w);
    }
#pragma unroll
    for (int mask = 32; mask >= 1; mask >>= 1) m = fmaxf(m, __shfl_xor(m, mask, 64));

    const float LOG2E = 1.4426950408889634f;
    float s = 0.0f;
#pragma unroll
    for (int j = 0; j < 4; ++j) {
        x[j].x = __builtin_amdgcn_exp2f((x[j].x - m) * LOG2E);
        x[j].y = __builtin_amdgcn_exp2f((x[j].y - m) * LOG2E);
        x[j].z = __builtin_amdgcn_exp2f((x[j].z - m) * LOG2E);
        x[j].w = __builtin_amdgcn_exp2f((x[j].w - m) * LOG2E);
        s += x[j].x + x[j].y + x[j].z + x[j].w;
    }
#pragma unroll
    for (int mask = 32; mask >= 1; mask >>= 1) s += __shfl_xor(s, mask, 64);
    const float r = __builtin_amdgcn_rcpf(s);
#pragma unroll
    for (int j = 0; j < 4; ++j) {
        x[j].x *= r; x[j].y *= r; x[j].z *= r; x[j].w *= r;
        *(float4*)(p + j * 256 + lane * 4) = x[j];
    }
}

extern "C" void kernel_launch(void* const* d_in, const int* in_sizes, int n_in,
                              void* d_out, int out_size, void* d_ws, size_t ws_size,
                              hipStream_t stream)
{
    const float* hidden = (const float*)d_in[0];  // [4,128,512]
    const float* ctx    = (const float*)d_in[1];  // [4,1024,512]
    const float* W      = (const float*)d_in[2];  // [512,512]
    const float* U      = (const float*)d_in[3];  // [512,512]
    const float* U_b    = (const float*)d_in[4];  // [512]
    const float* V      = (const float*)d_in[5];  // [512]
    float* out = (float*)d_out;                   // [4,128,1024]

    float* ewq_t = (float*)d_ws;                  // [4][512][128]  (1 MB)
    float* euc_t = ewq_t + 4 * 512 * 128;         // [4][512][1024] (8 MB)
    float* Wt    = euc_t + 4 * 512 * 1024;        // [512][512]     (1 MB)
    float* Ut    = Wt + 512 * 512;                // [512][512]     (1 MB)

    transpose512<<<dim3(8, 8, 2), 256, 0, stream>>>(W, U, Wt, Ut);
    gemm_sgpr_kernel<<<576, 256, 0, stream>>>(hidden, ctx, Wt, Ut, U_b, ewq_t, euc_t);
    fused_align3<<<dim3(16, 8, 4), 256, 0, stream>>>(ewq_t, euc_t, V, out);
    softmax_kernel<<<128, 256, 0, stream>>>(out);
}